// Round 11
// baseline (143.070 us; speedup 1.0000x reference)
//
#include <hip/hip_runtime.h>
#include <float.h>

// Batched 1D linear interpolation with clamped extrapolation.
// t: [B,N] sorted fp32, v: [B,N] fp32, r: [B,M] fp32 -> out: [B,M] fp32
constexpr int B = 2048;
constexpr int N = 4096;
constexpr int M = 4096;
constexpr int K = 4064;  // LDS: stv (N+8)*8 + lut K*2 = 32832 + 8128 = 40960 B EXACTLY
constexpr int T = 512;   // 4 blocks/CU x 8 waves = 32 waves/CU (the proven geometry)
// R9's depth-2 query structure (interleaved stv, b128 windows carrying both t
// and v -> no separate sv level) restored to R2's 4-block/CU geometry.
// Query phase is 4-wide x 2 passes to fit the 64-VGPR/8-wave cap honestly
// (R7 showed the allocator re-serializes anything wider under this cap).

__global__ __launch_bounds__(T, 8) void interp_kernel(
    const float* __restrict__ t,
    const float* __restrict__ v,
    const float* __restrict__ r,
    float* __restrict__ out) {
    __shared__ __align__(16) float2 stv[N + 8];  // (t,v); pad = (+inf, 0) sentinels
    __shared__ unsigned short lut[K];            // lut[k] = first j with bucket(t[j]) >= k (<= N-1)

    const int tid = threadIdx.x;
    const int b = blockIdx.x;
    const float* tb = t + (size_t)b * N;
    const float* vb = v + (size_t)b * N;
    const float4* r4 = (const float4*)(r + (size_t)b * M);
    float4* o4 = (float4*)(out + (size_t)b * M);

    // ALL global loads upfront: 6 float4s in one vmcnt group.
    const float4 t4a = ((const float4*)tb)[tid];
    const float4 t4b = ((const float4*)tb)[tid + T];
    const float4 v4a = ((const float4*)vb)[tid];
    const float4 v4b = ((const float4*)vb)[tid + T];
    const float4 qa = r4[tid];
    const float4 qb = r4[tid + T];

    if (tid < 8) stv[N + tid] = make_float2(FLT_MAX, 0.0f);

    // Commit interleaved (t,v): two b128 LDS writes per staged float4 pair.
    {
        float4* s4 = (float4*)stv;
        s4[2 * tid + 0]       = make_float4(t4a.x, v4a.x, t4a.y, v4a.y);
        s4[2 * tid + 1]       = make_float4(t4a.z, v4a.z, t4a.w, v4a.w);
        s4[2 * (tid + T) + 0] = make_float4(t4b.x, v4b.x, t4b.y, v4b.y);
        s4[2 * (tid + T) + 1] = make_float4(t4b.z, v4b.z, t4b.w, v4b.w);
    }

    // lut range-fill straight from staged registers (single barrier).
    // Element j claims buckets ((int)(t[j-1]*K), (int)(t[j]*K)]; disjoint,
    // tiles [0,K-1] (j==0 from 0, j==N-1 to K-1): no init pass, no races.
    {
        float tpa = __shfl_up(t4a.w, 1);
        if ((tid & 63) == 0 && tid > 0) tpa = tb[4 * tid - 1];
        float tpb = __shfl_up(t4b.w, 1);
        if ((tid & 63) == 0) tpb = tb[4 * (tid + T) - 1];
        const float pe[8] = {tpa, t4a.x, t4a.y, t4a.z, tpb, t4b.x, t4b.y, t4b.z};
        const float ce[8] = {t4a.x, t4a.y, t4a.z, t4a.w, t4b.x, t4b.y, t4b.z, t4b.w};
        #pragma unroll
        for (int e = 0; e < 8; ++e) {
            const int j = (e < 4 ? 4 * tid : 4 * (tid + T)) + (e & 3);
            int khi = (int)(ce[e] * (float)K);
            khi = khi > K - 1 ? K - 1 : khi;
            if (j == N - 1) khi = K - 1;        // claim the tail buckets
            const int klo = (j == 0) ? 0 : (int)(pe[e] * (float)K) + 1;
            for (int k = klo; k <= khi; ++k) lut[k] = (unsigned short)j;
        }
    }
    __syncthreads();

    const float tfirst = stv[0].x;
    const float vfirst = stv[0].y;
    const float tlast = stv[N - 1].x;
    const float vlast = stv[N - 1].y;

    const float q[8] = {qa.x, qa.y, qa.z, qa.w, qb.x, qb.y, qb.z, qb.w};
    float o[8];

    // Level 1 for BOTH passes hoisted: 8 independent u16 lut reads.
    // Invariant: all j < lut[k] have bucket(t[j]) < bucket(q) -> t[j] < q,
    // so t[b2] <= q (b2 <= lut[k]-1), except q < t[0] (fixed by final clamp).
    int b2[8];
    #pragma unroll
    for (int j = 0; j < 8; ++j) {
        int k = (int)(q[j] * (float)K);
        k = k < 0 ? 0 : (k > K - 1 ? K - 1 : k);
        int lo = lut[k];
        lo = lo < 1 ? 1 : lo;
        b2[j] = (lo - 1) & ~1;   // even float2 index -> 16B-aligned window
    }

    // Two 4-wide passes: window (8 independent ds_read_b128) -> resolve+math.
    #pragma unroll
    for (int pass = 0; pass < 2; ++pass) {
        float4 wA[4], wB[4];
        #pragma unroll
        for (int j = 0; j < 4; ++j) {
            const float4* w4 = (const float4*)(stv + b2[pass * 4 + j]);
            wA[j] = w4[0];   // (t,v) of window pos 0,1
            wB[j] = w4[1];   // pos 2,3
        }
        #pragma unroll
        for (int j = 0; j < 4; ++j) {
            const int jj = pass * 4 + j;
            const float qj = q[jj];
            const float ta0 = wA[j].x, ta1 = wA[j].z, ta2 = wB[j].x, ta3 = wB[j].z;
            int c = (ta0 <= qj ? 1 : 0) + (ta1 <= qj ? 1 : 0) +
                    (ta2 <= qj ? 1 : 0) + (ta3 <= qj ? 1 : 0);
            c = c < 1 ? 1 : c;   // q < t[0] handled by final clamp
            float t0 = (c >= 2) ? ((c >= 3) ? ta2 : ta1) : ta0;
            float t1 = (c >= 2) ? ((c >= 3) ? ta3 : ta2) : ta1;
            float v0 = (c >= 2) ? ((c >= 3) ? wB[j].y : wA[j].w) : wA[j].y;
            float v1 = (c >= 2) ? ((c >= 3) ? wB[j].w : wB[j].y) : wA[j].w;
            if (c == 4) {        // ~1.4%/query: transition past window (masked walk)
                float tp = ta3, vp = wB[j].w;
                int l = b2[jj] + 4;
                float2 cur = stv[l];
                while (cur.x <= qj) { tp = cur.x; vp = cur.y; ++l; cur = stv[l]; }
                t0 = tp; t1 = cur.x; v0 = vp; v1 = cur.y;   // inf sentinels bound
            }
            // idx==N corner: t1=inf -> rcp=0 -> oo=v[N-1]; matches reference.
            const float d = t1 - t0;
            const float rden = __builtin_amdgcn_rcpf(d == 0.0f ? 1.0f : d);
            float oo = v0 + (qj - t0) * rden * (v1 - v0);
            oo = (qj < tfirst) ? vfirst : oo;
            oo = (qj > tlast) ? vlast : oo;
            o[jj] = oo;
        }
    }
    o4[tid]     = make_float4(o[0], o[1], o[2], o[3]);
    o4[tid + T] = make_float4(o[4], o[5], o[6], o[7]);
}

extern "C" void kernel_launch(void* const* d_in, const int* in_sizes, int n_in,
                              void* d_out, int out_size, void* d_ws, size_t ws_size,
                              hipStream_t stream) {
    const float* t = (const float*)d_in[0];
    const float* v = (const float*)d_in[1];
    const float* r = (const float*)d_in[2];
    float* out = (float*)d_out;
    interp_kernel<<<B, T, 0, stream>>>(t, v, r, out);
}

// Round 12
// 138.884 us; speedup vs baseline: 1.0301x; 1.0301x over previous
//
#include <hip/hip_runtime.h>
#include <float.h>

// Batched 1D linear interpolation with clamped extrapolation.
// t: [B,N] sorted fp32, v: [B,N] fp32, r: [B,M] fp32 -> out: [B,M] fp32
constexpr int B = 2048;
constexpr int N = 4096;
constexpr int M = 4096;
constexpr int K = 4088;  // LDS: st (N+4)*4 + sv N*4 + lut K*2 = 16400+16384+8176 = 40960 B
constexpr int T = 512;   // 4 blocks/CU x 8 waves = 32 waves/CU
constexpr int BPB = 2;   // batches per block
constexpr int GRID = B / BPB;  // 1024 = 256 CU x 4 resident blocks
// Pipelining rationale: phases are serialized (VALU 37 + LDS ~35 + HBM ~25
// ~= 97%), HBM runs at 2.0/6.3 TB/s because it idles during query phases.
// Prefetch batch i+1's t/v into regs and keep the loads IN FLIGHT across the
// barriers: __syncthreads() would emit s_waitcnt vmcnt(0) (documented m97
// barrier drain) killing the overlap -- so barriers here are raw s_barrier
// with an lgkmcnt(0)-only wait (LDS producer/consumer safety), and the
// compiler places the vmcnt wait at the prefetch regs' consumption (next
// commit), exactly where it belongs.

__device__ __forceinline__ void wait_lgkm_barrier() {
    asm volatile("s_waitcnt lgkmcnt(0)" ::: "memory");
    __builtin_amdgcn_s_barrier();
    asm volatile("" ::: "memory");
}

__device__ __forceinline__ void commit_stage(float* st, float* sv, unsigned short* lut,
                                             float4 pt0, float4 pt1, float4 pv0, float4 pv1,
                                             int tid) {
    ((float4*)st)[tid]     = pt0;
    ((float4*)st)[tid + T] = pt1;
    ((float4*)sv)[tid]     = pv0;
    ((float4*)sv)[tid + T] = pv1;
    if (tid < 4) st[N + tid] = FLT_MAX;          // scan sentinels
    for (int i = tid; i < K / 2; i += T)          // packed u32 lut init
        ((unsigned int*)lut)[i] = ((unsigned)N << 16) | (unsigned)N;
}

__device__ __forceinline__ void fill_lut(const float* st, unsigned short* lut, int tid) {
    // Range-fill: element j claims buckets ((int)(t[j-1]*K), (int)(t[j]*K)].
    // Disjoint -> no races; u16 LDS writes are byte-enable safe.
    for (int j = tid; j < N; j += T) {
        const float tj = st[j];
        int khi = (int)(tj * (float)K);
        if (khi > K - 1) khi = K - 1;
        const int klo = (j > 0) ? (int)(st[j - 1] * (float)K) + 1 : 0;
        for (int k = klo; k <= khi; ++k) lut[k] = (unsigned short)j;
    }
}

__device__ __forceinline__ void do_queries(const float* st, const float* sv,
                                           const unsigned short* lut,
                                           float4 qa, float4 qb, float4* o4, int tid) {
    const float tfirst = st[0];
    const float vfirst = sv[0];
    const float tlast = st[N - 1];
    const float vlast = sv[N - 1];

    float q[8] = {qa.x, qa.y, qa.z, qa.w, qb.x, qb.y, qb.z, qb.w};
    int lo[8];

    // Phase 1: all 8 lut loads issued together.
    #pragma unroll
    for (int j = 0; j < 8; ++j) {
        int k = (int)(q[j] * (float)K);
        k = k < 0 ? 0 : (k > K - 1 ? K - 1 : k);
        lo[j] = lut[k];
    }
    // Phase 2: sentinel-bounded scan — 2 predicated steps + rare fallback.
    #pragma unroll
    for (int j = 0; j < 8; ++j) {
        lo[j] += (st[lo[j]] <= q[j]) ? 1 : 0;
        lo[j] += (st[lo[j]] <= q[j]) ? 1 : 0;
        while (st[lo[j]] <= q[j]) ++lo[j];
    }
    // Phase 3: final pair fetches (ds_read2_b32) + interp math (fast rcp).
    float o[8];
    #pragma unroll
    for (int j = 0; j < 8; ++j) {
        const int idx = lo[j] < 1 ? 1 : (lo[j] > N - 1 ? N - 1 : lo[j]);
        const float t0 = st[idx - 1];
        const float t1 = st[idx];
        const float v0 = sv[idx - 1];
        const float v1 = sv[idx];
        const float d = t1 - t0;
        const float rden = __builtin_amdgcn_rcpf(d == 0.0f ? 1.0f : d);
        float oo = v0 + (q[j] - t0) * rden * (v1 - v0);
        oo = (q[j] < tfirst) ? vfirst : oo;
        oo = (q[j] > tlast) ? vlast : oo;
        o[j] = oo;
    }
    o4[tid]     = make_float4(o[0], o[1], o[2], o[3]);
    o4[tid + T] = make_float4(o[4], o[5], o[6], o[7]);
}

__global__ __launch_bounds__(T, 8) void interp_kernel(
    const float* __restrict__ t,
    const float* __restrict__ v,
    const float* __restrict__ r,
    float* __restrict__ out) {
    __shared__ __align__(16) float st[N + 4];   // st[N..N+3] = +inf sentinels
    __shared__ __align__(16) float sv[N];
    __shared__ unsigned short lut[K];

    const int tid = threadIdx.x;
    const int b0 = blockIdx.x * BPB;

    // Prefetch batch 0 (t/v/r) — one vmcnt group.
    const float4* tbA = (const float4*)(t + (size_t)b0 * N);
    const float4* vbA = (const float4*)(v + (size_t)b0 * N);
    const float4* rbA = (const float4*)(r + (size_t)b0 * M);
    float4 At0 = tbA[tid], At1 = tbA[tid + T];
    float4 Av0 = vbA[tid], Av1 = vbA[tid + T];
    float4 qaA = rbA[tid], qbA = rbA[tid + T];

    // ---------------- batch 0 ----------------
    commit_stage(st, sv, lut, At0, At1, Av0, Av1, tid);

    // Issue batch-1 t/v prefetch NOW; these loads stay in flight across the
    // raw barriers + fill + the whole query phase of batch 0 (HBM overlap).
    const float4* tbB = (const float4*)(t + (size_t)(b0 + 1) * N);
    const float4* vbB = (const float4*)(v + (size_t)(b0 + 1) * N);
    float4 Bt0 = tbB[tid], Bt1 = tbB[tid + T];
    float4 Bv0 = vbB[tid], Bv1 = vbB[tid + T];

    wait_lgkm_barrier();
    fill_lut(st, lut, tid);
    wait_lgkm_barrier();
    do_queries(st, sv, lut, qaA, qbA, (float4*)(out + (size_t)b0 * M), tid);
    wait_lgkm_barrier();   // LDS reuse guard (readers done before overwrite)

    // ---------------- batch 1 ----------------
    const float4* rbB = (const float4*)(r + (size_t)(b0 + 1) * M);
    float4 qaB = rbB[tid], qbB = rbB[tid + T];   // hides under commit+fill

    commit_stage(st, sv, lut, Bt0, Bt1, Bv0, Bv1, tid);
    wait_lgkm_barrier();
    fill_lut(st, lut, tid);
    wait_lgkm_barrier();
    do_queries(st, sv, lut, qaB, qbB, (float4*)(out + (size_t)(b0 + 1) * M), tid);
}

extern "C" void kernel_launch(void* const* d_in, const int* in_sizes, int n_in,
                              void* d_out, int out_size, void* d_ws, size_t ws_size,
                              hipStream_t stream) {
    const float* t = (const float*)d_in[0];
    const float* v = (const float*)d_in[1];
    const float* r = (const float*)d_in[2];
    float* out = (float*)d_out;
    interp_kernel<<<GRID, T, 0, stream>>>(t, v, r, out);
}

// Round 13
// 136.433 us; speedup vs baseline: 1.0486x; 1.0180x over previous
//
#include <hip/hip_runtime.h>
#include <float.h>

// Batched 1D linear interpolation with clamped extrapolation.
// t: [B,N] sorted fp32, v: [B,N] fp32, r: [B,M] fp32 -> out: [B,M] fp32
constexpr int B = 2048;
constexpr int N = 4096;
constexpr int M = 4096;
constexpr int K = 4088;  // LDS: st (N+4)*4 + sv N*4 + lut K*2 = 16400+16384+8176 = 40960 B
constexpr int T = 512;   // 4 blocks/CU x 8 waves = 32 waves/CU
// De-phasing: all resident blocks start together and have IDENTICAL phase
// durations, so the whole chip runs [staging burst | query phase] in lockstep
// through every backfill round (VALU 37 + LDS ~38 + HBM ~25 ~= 100% = pipes
// time-sliced, never overlapped; HBM 4x oversubscribed during staging, idle
// during queries). Fix: round-1 blocks spin rank*PHASE/4 before their first
// global load. Uniform block duration makes backfill inherit the stagger, so
// the delay is paid once and HBM streams continuously for all 8 rounds.
constexpr long long STAGGER_CYC = 3100;  // ~ (block cycle 12.5K cyc) / 4

__global__ __launch_bounds__(T, 8) void interp_kernel(
    const float* __restrict__ t,
    const float* __restrict__ v,
    const float* __restrict__ r,
    float* __restrict__ out) {
    __shared__ __align__(16) float st[N + 4];       // st[N..N+3] = +inf sentinels
    __shared__ __align__(16) float sv[N];
    __shared__ unsigned short lut[K];               // lut[k] = first j with (int)(t[j]*K) >= k; else N

    const int tid = threadIdx.x;
    const int b = blockIdx.x;

    // Stagger preamble: only the first resident round (in-order dispatch ->
    // blockIdx < 1024), BEFORE any global load is issued. Rank extraction
    // gives distinct ranks to co-resident blocks under both packed
    // (CU = b/4) and round-robin (CU = b%256) dispatch mappings.
    if (b < 1024) {
        const int rank = ((b & 3) + (b >> 8)) & 3;
        if (rank) {
            const long long tgt = (long long)rank * STAGGER_CYC;
            const long long t0 = clock64();
            while (clock64() - t0 < tgt) { }
        }
    }

    const float* tb = t + (size_t)b * N;
    const float* vb = v + (size_t)b * N;
    const float* rb = r + (size_t)b * M;
    float* ob = out + (size_t)b * M;

    // Queries first: HBM latency hides under staging + lut fill.
    const float4* r4 = (const float4*)rb;
    const int ia = tid;
    const int ib = ia + T;
    const float4 qa = r4[ia];
    const float4 qb = r4[ib];

    // Stage t/v with coalesced float4 loads; init lut; plant sentinels.
    for (int i = tid; i < N / 4; i += T) {
        ((float4*)st)[i] = ((const float4*)tb)[i];
        ((float4*)sv)[i] = ((const float4*)vb)[i];
    }
    if (tid == 0) { st[N] = FLT_MAX; st[N + 1] = FLT_MAX; }
    for (int k = tid; k < K; k += T) lut[k] = (unsigned short)N;
    __syncthreads();

    // Range-fill: element j claims buckets ((int)(t[j-1]*K), (int)(t[j]*K)].
    // Disjoint ranges -> no races; u16 LDS writes are byte-enable safe.
    for (int j = tid; j < N; j += T) {
        const float tj = st[j];
        int khi = (int)(tj * (float)K);
        if (khi > K - 1) khi = K - 1;
        const int klo = (j > 0) ? (int)(st[j - 1] * (float)K) + 1 : 0;
        for (int k = klo; k <= khi; ++k) lut[k] = (unsigned short)j;
    }
    __syncthreads();

    const float tfirst = st[0];
    const float vfirst = sv[0];
    const float tlast = st[N - 1];
    const float vlast = sv[N - 1];

    float q[8] = {qa.x, qa.y, qa.z, qa.w, qb.x, qb.y, qb.z, qb.w};
    int lo[8];

    // Phase 1: all 8 lut loads issued together (u16, random over all banks).
    // Invariant: t[lo-1] <= q (strict bucket math), so scan starts at lo.
    #pragma unroll
    for (int j = 0; j < 8; ++j) {
        int k = (int)(q[j] * (float)K);
        k = k < 0 ? 0 : (k > K - 1 ? K - 1 : k);
        lo[j] = lut[k];
    }
    // Phase 2: sentinel-bounded scan — no clamp, no bounds check.
    // K~N means ~1 point/bucket: 2 predicated steps, rare fallback.
    #pragma unroll
    for (int j = 0; j < 8; ++j) {
        lo[j] += (st[lo[j]] <= q[j]) ? 1 : 0;
        lo[j] += (st[lo[j]] <= q[j]) ? 1 : 0;
        while (st[lo[j]] <= q[j]) ++lo[j];
    }
    // Phase 3: final pair fetches (ds_read2_b32) + interp math (fast rcp).
    float o[8];
    #pragma unroll
    for (int j = 0; j < 8; ++j) {
        const int idx = lo[j] < 1 ? 1 : (lo[j] > N - 1 ? N - 1 : lo[j]);
        const float t0 = st[idx - 1];
        const float t1 = st[idx];
        const float v0 = sv[idx - 1];
        const float v1 = sv[idx];
        const float d = t1 - t0;
        const float rden = __builtin_amdgcn_rcpf(d == 0.0f ? 1.0f : d);
        float oo = v0 + (q[j] - t0) * rden * (v1 - v0);
        oo = (q[j] < tfirst) ? vfirst : oo;
        oo = (q[j] > tlast) ? vlast : oo;
        o[j] = oo;
    }
    float4* o4 = (float4*)ob;
    o4[ia] = make_float4(o[0], o[1], o[2], o[3]);
    o4[ib] = make_float4(o[4], o[5], o[6], o[7]);
}

extern "C" void kernel_launch(void* const* d_in, const int* in_sizes, int n_in,
                              void* d_out, int out_size, void* d_ws, size_t ws_size,
                              hipStream_t stream) {
    const float* t = (const float*)d_in[0];
    const float* v = (const float*)d_in[1];
    const float* r = (const float*)d_in[2];
    float* out = (float*)d_out;
    interp_kernel<<<B, T, 0, stream>>>(t, v, r, out);
}